// Round 1
// baseline (836.648 us; speedup 1.0000x reference)
//
#include <hip/hip_runtime.h>

#define T_STEPS 512
#define BATCH   2048
#define HID     64
#define IN0     8

// tanh(x) = 1 - 2/(exp(2x)+1); exp via v_exp_f32, rcp via v_rcp_f32.
// Handles saturation correctly: x>>0 -> exp=inf -> rcp=0 -> 1; x<<0 -> exp=0 -> -1.
__device__ __forceinline__ float tanh_fast(float x) {
    float e = __builtin_amdgcn_exp2f(x * 2.885390081777927f); // exp(2x) = 2^(2x*log2e)
    return 1.0f - 2.0f * __builtin_amdgcn_rcpf(e + 1.0f);
}

__global__ __launch_bounds__(64, 2)
void rnn2_fused(const float* __restrict__ x,
                const float* __restrict__ Wih0,
                const float* __restrict__ Whh0,
                const float* __restrict__ bih0,
                const float* __restrict__ bhh0,
                const float* __restrict__ Wih1,
                const float* __restrict__ Whh1,
                const float* __restrict__ bih1,
                const float* __restrict__ bhh1,
                const float* __restrict__ fcw,
                const float* __restrict__ fcb,
                float* __restrict__ out) {
    const int j = threadIdx.x;   // hidden unit 0..63 (lane)
    const int b = blockIdx.x;    // sequence

    __shared__ __align__(16) float h0s[HID];
    __shared__ __align__(16) float h1s[HID];

    // --- weights for row j into registers (50 float4 = 200 VGPRs) ---
    float4 wih0[2], whh0[16], wih1[16], whh1[16];
    {
        const float4* p0 = (const float4*)(Wih0 + j * IN0);
        wih0[0] = p0[0]; wih0[1] = p0[1];
        const float4* p1 = (const float4*)(Whh0 + j * HID);
        #pragma unroll
        for (int q = 0; q < 16; ++q) whh0[q] = p1[q];
        const float4* p2 = (const float4*)(Wih1 + j * HID);
        #pragma unroll
        for (int q = 0; q < 16; ++q) wih1[q] = p2[q];
        const float4* p3 = (const float4*)(Whh1 + j * HID);
        #pragma unroll
        for (int q = 0; q < 16; ++q) whh1[q] = p3[q];
    }

    const float b0s  = bih0[j] + bhh0[j];
    const float b1s  = bih1[j] + bhh1[j];
    const float fcwj = fcw[j];

    h1s[j] = 0.0f;                       // h1_{-1} = 0
    __builtin_amdgcn_wave_barrier();

    const float* xrow = x + (size_t)b * (T_STEPS * IN0);
    float4 xa = ((const float4*)xrow)[0];
    float4 xb = ((const float4*)xrow)[1];

    float pre0_acc = b0s;                // b0 + Whh0·h0_{-1} (=0)
    float h1 = 0.0f;

    for (int t = 0; t < T_STEPS; ++t) {
        // prefetch next timestep's x (wave-uniform, 32B)
        const int tn = (t + 1 < T_STEPS) ? (t + 1) : (T_STEPS - 1);
        const float4 nxa = ((const float4*)(xrow + tn * IN0))[0];
        const float4 nxb = ((const float4*)(xrow + tn * IN0))[1];

        // layer 0: pre0 = (b0 + Whh0·h0_{t-1}) + Wih0·x_t
        float pre0 = pre0_acc;
        pre0 += xa.x * wih0[0].x + xa.y * wih0[0].y + xa.z * wih0[0].z + xa.w * wih0[0].w;
        pre0 += xb.x * wih0[1].x + xb.y * wih0[1].y + xb.z * wih0[1].z + xb.w * wih0[1].w;
        const float h0 = tanh_fast(pre0);

        h0s[j] = h0;                     // publish h0_t
        __builtin_amdgcn_wave_barrier(); // keep write before the broadcast reads

        // broadcast h0_t once; feed BOTH Wih1 (this step) and Whh0 (next step)
        float pre1 = b1s;
        pre0_acc = b0s;
        const float4* h0v = (const float4*)h0s;
        #pragma unroll
        for (int c = 0; c < 16; ++c) {
            const float4 hv = h0v[c];
            pre1     += hv.x * wih1[c].x + hv.y * wih1[c].y + hv.z * wih1[c].z + hv.w * wih1[c].w;
            pre0_acc += hv.x * whh0[c].x + hv.y * whh0[c].y + hv.z * whh0[c].z + hv.w * whh0[c].w;
        }
        // broadcast h1_{t-1} (still in LDS from last iter)
        const float4* h1v = (const float4*)h1s;
        #pragma unroll
        for (int c = 0; c < 16; ++c) {
            const float4 hv = h1v[c];
            pre1 += hv.x * whh1[c].x + hv.y * whh1[c].y + hv.z * whh1[c].z + hv.w * whh1[c].w;
        }
        h1 = tanh_fast(pre1);
        __builtin_amdgcn_wave_barrier(); // reads of h1s above must precede this write
        h1s[j] = h1;                     // publish h1_t

        xa = nxa; xb = nxb;
    }

    // FC head: out[b] = sum_j h1_T[j] * fcw[j] + fcb
    float v = h1 * fcwj;
    #pragma unroll
    for (int off = 32; off > 0; off >>= 1)
        v += __shfl_xor(v, off, 64);
    if (j == 0) out[b] = v + fcb[0];
}

extern "C" void kernel_launch(void* const* d_in, const int* in_sizes, int n_in,
                              void* d_out, int out_size, void* d_ws, size_t ws_size,
                              hipStream_t stream) {
    const float* x    = (const float*)d_in[0];
    const float* Wih0 = (const float*)d_in[1];
    const float* Whh0 = (const float*)d_in[2];
    const float* bih0 = (const float*)d_in[3];
    const float* bhh0 = (const float*)d_in[4];
    const float* Wih1 = (const float*)d_in[5];
    const float* Whh1 = (const float*)d_in[6];
    const float* bih1 = (const float*)d_in[7];
    const float* bhh1 = (const float*)d_in[8];
    const float* fcw  = (const float*)d_in[9];
    const float* fcb  = (const float*)d_in[10];
    float* out = (float*)d_out;

    rnn2_fused<<<dim3(BATCH), dim3(64), 0, stream>>>(
        x, Wih0, Whh0, bih0, bhh0, Wih1, Whh1, bih1, bhh1, fcw, fcb, out);
}

// Round 2
// 713.592 us; speedup vs baseline: 1.1724x; 1.1724x over previous
//
#include <hip/hip_runtime.h>

#define T_STEPS 512
#define BATCH   2048
#define HID     64
#define IN0     8

// tanh(x) = 1 - 2/(exp(2x)+1); saturates correctly at +/-inf.
__device__ __forceinline__ float tanh_fast(float x) {
    float e = __builtin_amdgcn_exp2f(x * 2.885390081777927f); // exp(2x)
    return 1.0f - 2.0f * __builtin_amdgcn_rcpf(e + 1.0f);
}

// Broadcast lane `lane`'s value of v to all lanes via v_readlane (SGPR result,
// no DS pipe, no VGPR pressure). lane must be a compile-time constant here.
__device__ __forceinline__ float bcast(float v, int lane) {
    return __int_as_float(__builtin_amdgcn_readlane(__float_as_int(v), lane));
}

__global__ __launch_bounds__(64, 2)
void rnn2_fused(const float* __restrict__ x,
                const float* __restrict__ Wih0,
                const float* __restrict__ Whh0,
                const float* __restrict__ bih0,
                const float* __restrict__ bhh0,
                const float* __restrict__ Wih1,
                const float* __restrict__ Whh1,
                const float* __restrict__ bih1,
                const float* __restrict__ bhh1,
                const float* __restrict__ fcw,
                const float* __restrict__ fcb,
                float* __restrict__ out) {
    const int j = threadIdx.x;   // hidden unit (lane)
    const int b = blockIdx.x;    // sequence

    // ---- per-lane weight rows into registers (200 VGPRs) ----
    float wih0[IN0], whh0[HID], wih1[HID], whh1[HID];
    {
        const float4* p = (const float4*)(Wih0 + j * IN0);
        #pragma unroll
        for (int q = 0; q < IN0 / 4; ++q) {
            float4 v = p[q];
            wih0[4*q+0] = v.x; wih0[4*q+1] = v.y; wih0[4*q+2] = v.z; wih0[4*q+3] = v.w;
        }
    }
    {
        const float4* p = (const float4*)(Whh0 + j * HID);
        #pragma unroll
        for (int q = 0; q < HID / 4; ++q) {
            float4 v = p[q];
            whh0[4*q+0] = v.x; whh0[4*q+1] = v.y; whh0[4*q+2] = v.z; whh0[4*q+3] = v.w;
        }
    }
    {
        const float4* p = (const float4*)(Wih1 + j * HID);
        #pragma unroll
        for (int q = 0; q < HID / 4; ++q) {
            float4 v = p[q];
            wih1[4*q+0] = v.x; wih1[4*q+1] = v.y; wih1[4*q+2] = v.z; wih1[4*q+3] = v.w;
        }
    }
    {
        const float4* p = (const float4*)(Whh1 + j * HID);
        #pragma unroll
        for (int q = 0; q < HID / 4; ++q) {
            float4 v = p[q];
            whh1[4*q+0] = v.x; whh1[4*q+1] = v.y; whh1[4*q+2] = v.z; whh1[4*q+3] = v.w;
        }
    }

    const float b0s  = bih0[j] + bhh0[j];
    const float b1s  = bih1[j] + bhh1[j];
    const float fcwj = fcw[j];
    const float fcb0 = fcb[0];

    // Forbid sinking the (loop-invariant) weight loads into the t-loop:
    // the asm may write memory, so loads can't be re-executed after it.
    asm volatile("" ::: "memory");

    const float* xrow = x + (size_t)b * (T_STEPS * IN0);
    float4 xa = ((const float4*)xrow)[0];
    float4 xb = ((const float4*)xrow)[1];

    float pre0_acc = b0s;   // b0 + Whh0·h0_{t-1}, maintained one step ahead
    float h1 = 0.0f;        // h1_{t-1}, lane j holds component j

    for (int t = 0; t < T_STEPS; ++t) {
        const int tn = (t + 1 < T_STEPS) ? (t + 1) : (T_STEPS - 1);
        const float4 nxa = ((const float4*)(xrow + tn * IN0))[0];
        const float4 nxb = ((const float4*)(xrow + tn * IN0))[1];

        // layer 0: pre0 = (b0 + Whh0·h0_{t-1}) + Wih0·x_t
        float pre0 = pre0_acc;
        pre0 = fmaf(xa.x, wih0[0], pre0); pre0 = fmaf(xa.y, wih0[1], pre0);
        pre0 = fmaf(xa.z, wih0[2], pre0); pre0 = fmaf(xa.w, wih0[3], pre0);
        pre0 = fmaf(xb.x, wih0[4], pre0); pre0 = fmaf(xb.y, wih0[5], pre0);
        pre0 = fmaf(xb.z, wih0[6], pre0); pre0 = fmaf(xb.w, wih0[7], pre0);
        const float h0 = tanh_fast(pre0);

        // Broadcast h0 once per k; feed BOTH Wih1 (this step) and Whh0 (next).
        // Two accumulator chains each to expose ILP.
        float p1a = 0.0f, p1b = 0.0f, a0a = 0.0f, a0b = 0.0f;
        #pragma unroll
        for (int k = 0; k < HID; k += 2) {
            const float ha = bcast(h0, k);
            const float hb = bcast(h0, k + 1);
            p1a = fmaf(wih1[k],     ha, p1a);
            a0a = fmaf(whh0[k],     ha, a0a);
            p1b = fmaf(wih1[k + 1], hb, p1b);
            a0b = fmaf(whh0[k + 1], hb, a0b);
        }

        // Whh1 · h1_{t-1}
        float p2a = 0.0f, p2b = 0.0f;
        #pragma unroll
        for (int k = 0; k < HID; k += 2) {
            const float ha = bcast(h1, k);
            const float hb = bcast(h1, k + 1);
            p2a = fmaf(whh1[k],     ha, p2a);
            p2b = fmaf(whh1[k + 1], hb, p2b);
        }

        h1 = tanh_fast(b1s + (p1a + p1b) + (p2a + p2b));
        pre0_acc = b0s + (a0a + a0b);

        xa = nxa; xb = nxb;
    }

    // FC head: out[b] = sum_j h1[j] * fcw[j] + fcb
    float v = h1 * fcwj;
    #pragma unroll
    for (int off = 32; off > 0; off >>= 1)
        v += __shfl_xor(v, off, 64);
    if (j == 0) out[b] = v + fcb0;
}

extern "C" void kernel_launch(void* const* d_in, const int* in_sizes, int n_in,
                              void* d_out, int out_size, void* d_ws, size_t ws_size,
                              hipStream_t stream) {
    const float* x    = (const float*)d_in[0];
    const float* Wih0 = (const float*)d_in[1];
    const float* Whh0 = (const float*)d_in[2];
    const float* bih0 = (const float*)d_in[3];
    const float* bhh0 = (const float*)d_in[4];
    const float* Wih1 = (const float*)d_in[5];
    const float* Whh1 = (const float*)d_in[6];
    const float* bih1 = (const float*)d_in[7];
    const float* bhh1 = (const float*)d_in[8];
    const float* fcw  = (const float*)d_in[9];
    const float* fcb  = (const float*)d_in[10];
    float* out = (float*)d_out;

    rnn2_fused<<<dim3(BATCH), dim3(64), 0, stream>>>(
        x, Wih0, Whh0, bih0, bhh0, Wih1, Whh1, bih1, bhh1, fcw, fcb, out);
}

// Round 3
// 517.775 us; speedup vs baseline: 1.6159x; 1.3782x over previous
//
#include <hip/hip_runtime.h>

#define T_STEPS 512
#define BATCH   2048
#define HID     64
#define IN0     8

typedef _Float16 half2 __attribute__((ext_vector_type(2)));

// tanh(x) = 1 - 2/(exp(2x)+1); saturates correctly at +/-inf.
__device__ __forceinline__ float tanh_fast(float x) {
    float e = __builtin_amdgcn_exp2f(x * 2.885390081777927f); // exp(2x)
    return 1.0f - 2.0f * __builtin_amdgcn_rcpf(e + 1.0f);
}

#if __has_builtin(__builtin_amdgcn_fdot2)
#define FDOT2(w, h, acc) __builtin_amdgcn_fdot2((w), (h), (acc), false)
#else
__device__ __forceinline__ float FDOT2(half2 w, half2 h, float a) {
    return fmaf((float)w.x, (float)h.x, fmaf((float)w.y, (float)h.y, a));
}
#endif

// pack two f32 into f16 pair (RNE) — init-time only
__device__ __forceinline__ int pack_rne(float a, float b) {
    half2 r;
    r.x = (_Float16)a;
    r.y = (_Float16)b;
    return __builtin_bit_cast(int, r);
}

__global__ __launch_bounds__(64, 2)
void rnn2_fused(const float* __restrict__ x,
                const float* __restrict__ Wih0,
                const float* __restrict__ Whh0,
                const float* __restrict__ bih0,
                const float* __restrict__ bhh0,
                const float* __restrict__ Wih1,
                const float* __restrict__ Whh1,
                const float* __restrict__ bih1,
                const float* __restrict__ bhh1,
                const float* __restrict__ fcw,
                const float* __restrict__ fcb,
                float* __restrict__ out) {
    const int j = threadIdx.x;   // hidden unit (lane)
    const int b = blockIdx.x;    // sequence

    // ---- per-lane weight rows: f16 pairs, 32 regs per HxH matrix ----
    float wih0[IN0];
    int whh0p[HID / 2], wih1p[HID / 2], whh1p[HID / 2];
    {
        const float4* p = (const float4*)(Wih0 + j * IN0);
        #pragma unroll
        for (int q = 0; q < IN0 / 4; ++q) {
            float4 v = p[q];
            wih0[4*q+0] = v.x; wih0[4*q+1] = v.y; wih0[4*q+2] = v.z; wih0[4*q+3] = v.w;
        }
        const float4* p0 = (const float4*)(Whh0 + j * HID);
        const float4* p1 = (const float4*)(Wih1 + j * HID);
        const float4* p2 = (const float4*)(Whh1 + j * HID);
        #pragma unroll
        for (int q = 0; q < HID / 4; ++q) {
            float4 v0 = p0[q], v1 = p1[q], v2 = p2[q];
            whh0p[2*q]   = pack_rne(v0.x, v0.y);
            whh0p[2*q+1] = pack_rne(v0.z, v0.w);
            wih1p[2*q]   = pack_rne(v1.x, v1.y);
            wih1p[2*q+1] = pack_rne(v1.z, v1.w);
            whh1p[2*q]   = pack_rne(v2.x, v2.y);
            whh1p[2*q+1] = pack_rne(v2.z, v2.w);
        }
    }

    float b0s  = bih0[j] + bhh0[j];
    float b1s  = bih1[j] + bhh1[j];
    float fcwj = fcw[j];
    const float fcb0 = fcb[0];

    // ---- PIN: make every weight an asm-produced value. The loop body can
    // no longer rematerialize them from memory; they must stay in VGPRs. ----
    #pragma unroll
    for (int m = 0; m < IN0; ++m) asm volatile("" : "+v"(wih0[m]));
    #pragma unroll
    for (int m = 0; m < HID / 2; ++m) {
        asm volatile("" : "+v"(whh0p[m]));
        asm volatile("" : "+v"(wih1p[m]));
        asm volatile("" : "+v"(whh1p[m]));
    }
    asm volatile("" : "+v"(b0s), "+v"(b1s), "+v"(fcwj));

    const float* xrow = x + (size_t)b * (T_STEPS * IN0);
    float4 xa = ((const float4*)xrow)[0];
    float4 xb = ((const float4*)xrow)[1];

    // pair-gather shuffle indices: lane j collects h[2j], h[2j+1]
    const int idx_e = (2 * j) & 63;
    const int idx_o = (2 * j + 1) & 63;

    float pre0_acc = b0s;   // b0 + Whh0·h0_{t-1}, maintained one step ahead
    int h1p = 0;            // packed f16 pair (h1[2j], h1[2j+1]) of h1_{t-1}
    float h1 = 0.0f;

    for (int t = 0; t < T_STEPS; ++t) {
        const int tn = (t + 1 < T_STEPS) ? (t + 1) : (T_STEPS - 1);
        const float4 nxa = ((const float4*)(xrow + tn * IN0))[0];
        const float4 nxb = ((const float4*)(xrow + tn * IN0))[1];

        // layer 0: pre0 = (b0 + Whh0·h0_{t-1}) + Wih0·x_t   (fp32 path)
        float pre0 = pre0_acc;
        pre0 = fmaf(xa.x, wih0[0], pre0); pre0 = fmaf(xa.y, wih0[1], pre0);
        pre0 = fmaf(xa.z, wih0[2], pre0); pre0 = fmaf(xa.w, wih0[3], pre0);
        pre0 = fmaf(xb.x, wih0[4], pre0); pre0 = fmaf(xb.y, wih0[5], pre0);
        pre0 = fmaf(xb.z, wih0[6], pre0); pre0 = fmaf(xb.w, wih0[7], pre0);
        const float h0 = tanh_fast(pre0);

        // gather h0 pair into lane j, pack to f16x2 (1 instr)
        const float h0e = __shfl(h0, idx_e, 64);
        const float h0o = __shfl(h0, idx_o, 64);
        const int h0p = __builtin_bit_cast(int, __builtin_amdgcn_cvt_pkrtz(h0e, h0o));

        // broadcast each pair once (readlane -> SGPR), feed BOTH Wih1 (this
        // step) and Whh0 (next step). Two acc chains each for ILP.
        float p1a = 0.0f, p1b = 0.0f, a0a = 0.0f, a0b = 0.0f;
        float p2a = 0.0f, p2b = 0.0f;
        #pragma unroll
        for (int m = 0; m < HID / 2; m += 2) {
            const half2 ha = __builtin_bit_cast(half2, __builtin_amdgcn_readlane(h0p, m));
            const half2 hb = __builtin_bit_cast(half2, __builtin_amdgcn_readlane(h0p, m + 1));
            p1a = FDOT2(__builtin_bit_cast(half2, wih1p[m]),     ha, p1a);
            a0a = FDOT2(__builtin_bit_cast(half2, whh0p[m]),     ha, a0a);
            p1b = FDOT2(__builtin_bit_cast(half2, wih1p[m + 1]), hb, p1b);
            a0b = FDOT2(__builtin_bit_cast(half2, whh0p[m + 1]), hb, a0b);
        }
        // Whh1 · h1_{t-1} from last iteration's packed pairs
        #pragma unroll
        for (int m = 0; m < HID / 2; m += 2) {
            const half2 ha = __builtin_bit_cast(half2, __builtin_amdgcn_readlane(h1p, m));
            const half2 hb = __builtin_bit_cast(half2, __builtin_amdgcn_readlane(h1p, m + 1));
            p2a = FDOT2(__builtin_bit_cast(half2, whh1p[m]),     ha, p2a);
            p2b = FDOT2(__builtin_bit_cast(half2, whh1p[m + 1]), hb, p2b);
        }

        h1 = tanh_fast(b1s + (p1a + p1b) + (p2a + p2b));
        pre0_acc = b0s + (a0a + a0b);

        // pack h1_t pairs for next step (latency hidden across loop back-edge)
        const float h1e = __shfl(h1, idx_e, 64);
        const float h1o = __shfl(h1, idx_o, 64);
        h1p = __builtin_bit_cast(int, __builtin_amdgcn_cvt_pkrtz(h1e, h1o));

        xa = nxa; xb = nxb;
    }

    // FC head: out[b] = sum_j h1[j] * fcw[j] + fcb
    float v = h1 * fcwj;
    #pragma unroll
    for (int off = 32; off > 0; off >>= 1)
        v += __shfl_xor(v, off, 64);
    if (j == 0) out[b] = v + fcb0;
}

extern "C" void kernel_launch(void* const* d_in, const int* in_sizes, int n_in,
                              void* d_out, int out_size, void* d_ws, size_t ws_size,
                              hipStream_t stream) {
    const float* x    = (const float*)d_in[0];
    const float* Wih0 = (const float*)d_in[1];
    const float* Whh0 = (const float*)d_in[2];
    const float* bih0 = (const float*)d_in[3];
    const float* bhh0 = (const float*)d_in[4];
    const float* Wih1 = (const float*)d_in[5];
    const float* Whh1 = (const float*)d_in[6];
    const float* bih1 = (const float*)d_in[7];
    const float* bhh1 = (const float*)d_in[8];
    const float* fcw  = (const float*)d_in[9];
    const float* fcb  = (const float*)d_in[10];
    float* out = (float*)d_out;

    rnn2_fused<<<dim3(BATCH), dim3(64), 0, stream>>>(
        x, Wih0, Whh0, bih0, bhh0, Wih1, Whh1, bih1, bhh1, fcw, fcb, out);
}

// Round 4
// 479.508 us; speedup vs baseline: 1.7448x; 1.0798x over previous
//
#include <hip/hip_runtime.h>

#define T_STEPS 512
#define BATCH   2048
#define HID     64
#define IN0     8
#define SPW     16              // sequences per wave (MFMA N dim)
#define NBLK    (BATCH / SPW)   // 128 blocks, 1 wave each

typedef _Float16 h2 __attribute__((ext_vector_type(2)));
typedef _Float16 h4 __attribute__((ext_vector_type(4)));
typedef _Float16 h8 __attribute__((ext_vector_type(8)));
typedef float    f4 __attribute__((ext_vector_type(4)));

#define MFMA(a, b, c) __builtin_amdgcn_mfma_f32_16x16x32_f16((a), (b), (c), 0, 0, 0)

union F8 { h8 v; h2 p[4]; };
union H4U { h4 v; h2 p[2]; };

__device__ __forceinline__ h2 pkrtz(float a, float b) {
    return __builtin_bit_cast(h2, __builtin_amdgcn_cvt_pkrtz(a, b));
}

// tanh(x) = 1 - 2/(exp(2x)+1); saturates correctly at +/-inf.
__device__ __forceinline__ float tanh_fast(float x) {
    float e = __builtin_amdgcn_exp2f(x * 2.885390081777927f);
    return 1.0f - 2.0f * __builtin_amdgcn_rcpf(e + 1.0f);
}

__global__ __launch_bounds__(64, 1)
void rnn2_mfma(const float* __restrict__ x,
               const float* __restrict__ Wih0, const float* __restrict__ Whh0,
               const float* __restrict__ bih0, const float* __restrict__ bhh0,
               const float* __restrict__ Wih1, const float* __restrict__ Whh1,
               const float* __restrict__ bih1, const float* __restrict__ bhh1,
               const float* __restrict__ fcw,  const float* __restrict__ fcb,
               float* __restrict__ out) {
    const int lane = threadIdx.x;
    const int n = lane & 15;   // A row-in-tile (m) / B,C column (sequence)
    const int q = lane >> 4;   // quad: k-block for A/B, row-block for C
    const int bseq = blockIdx.x * SPW;

    // relayout buffers: H stored [n][k] f16, k-stride 72 (+8 pad kills bank conflicts)
    __shared__ __align__(16) _Float16 Hb[2][SPW * 72];

    // ---- resident A-fragments (f16): frag[mt][kt], slot j <-> k = 32kt+8q+j ----
    h8 wh0[4][2], wi1[4][2], wh1[4][2];
    #pragma unroll
    for (int mt = 0; mt < 4; ++mt) {
        const int row = 16 * mt + n;
        #pragma unroll
        for (int kt = 0; kt < 2; ++kt) {
            const int k0 = 32 * kt + 8 * q;
            {
                const float4* p = (const float4*)(Whh0 + row * HID + k0);
                float4 a = p[0], b = p[1];
                F8 f; f.p[0] = pkrtz(a.x, a.y); f.p[1] = pkrtz(a.z, a.w);
                      f.p[2] = pkrtz(b.x, b.y); f.p[3] = pkrtz(b.z, b.w);
                wh0[mt][kt] = f.v;
            }
            {
                const float4* p = (const float4*)(Wih1 + row * HID + k0);
                float4 a = p[0], b = p[1];
                F8 f; f.p[0] = pkrtz(a.x, a.y); f.p[1] = pkrtz(a.z, a.w);
                      f.p[2] = pkrtz(b.x, b.y); f.p[3] = pkrtz(b.z, b.w);
                wi1[mt][kt] = f.v;
            }
            {
                const float4* p = (const float4*)(Whh1 + row * HID + k0);
                float4 a = p[0], b = p[1];
                F8 f; f.p[0] = pkrtz(a.x, a.y); f.p[1] = pkrtz(a.z, a.w);
                      f.p[2] = pkrtz(b.x, b.y); f.p[3] = pkrtz(b.z, b.w);
                wh1[mt][kt] = f.v;
            }
        }
    }
    // Wih0 (64x8), K padded: slot j=0 holds k=2q,2q+1; slots 1..3 zero.
    // X B-frag uses the SAME placement -> consistent regardless of true k-map.
    h8 wi0[4];
    #pragma unroll
    for (int mt = 0; mt < 4; ++mt) {
        const float2 w = *(const float2*)(Wih0 + (16 * mt + n) * IN0 + 2 * q);
        F8 f; f.p[0] = pkrtz(w.x, w.y);
        f.p[1] = pkrtz(0.f, 0.f); f.p[2] = f.p[1]; f.p[3] = f.p[1];
        wi0[mt] = f.v;
    }

    // biases as MFMA C-init: C reg r <-> row 16mt + 4q + r (verified C/D map)
    f4 bias0[4], bias1[4];
    #pragma unroll
    for (int mt = 0; mt < 4; ++mt)
        #pragma unroll
        for (int r = 0; r < 4; ++r) {
            const int i = 16 * mt + 4 * q + r;
            bias0[mt][r] = bih0[i] + bhh0[i];
            bias1[mt][r] = bih1[i] + bhh1[i];
        }

    // x: lane (q,n) streams x[bseq+n][t][2q..2q+1]
    const float* xp = x + ((size_t)(bseq + n) * T_STEPS) * IN0 + 2 * q;
    float2 xc = *(const float2*)xp;

    h8 h0f[2] = {}; h8 h1f[2] = {};   // h_{-1} = 0

    for (int t = 0; t < T_STEPS; ++t) {
        const int tn = (t + 1 < T_STEPS) ? t + 1 : t;
        const float2 xnx = *(const float2*)(xp + tn * IN0);

        F8 xf; xf.p[0] = pkrtz(xc.x, xc.y);
        xf.p[1] = pkrtz(0.f, 0.f); xf.p[2] = xf.p[1]; xf.p[3] = xf.p[1];

        // ---- layer 0: H0 = tanh(b0 + Wih0@x_t + Whh0@H0) ----
        f4 a0[4];
        #pragma unroll
        for (int mt = 0; mt < 4; ++mt) a0[mt] = MFMA(wi0[mt], xf.v, bias0[mt]);
        #pragma unroll
        for (int mt = 0; mt < 4; ++mt) a0[mt] = MFMA(wh0[mt][0], h0f[0], a0[mt]);
        #pragma unroll
        for (int mt = 0; mt < 4; ++mt) a0[mt] = MFMA(wh0[mt][1], h0f[1], a0[mt]);
        #pragma unroll
        for (int mt = 0; mt < 4; ++mt) {
            H4U u;
            u.p[0] = pkrtz(tanh_fast(a0[mt][0]), tanh_fast(a0[mt][1]));
            u.p[1] = pkrtz(tanh_fast(a0[mt][2]), tanh_fast(a0[mt][3]));
            *(h4*)&Hb[0][n * 72 + mt * 16 + q * 4] = u.v;   // k = 16mt+4q+(0..3)
        }
        __builtin_amdgcn_wave_barrier();
        h8 nh0f[2];
        #pragma unroll
        for (int kt = 0; kt < 2; ++kt)
            nh0f[kt] = *(const h8*)&Hb[0][n * 72 + kt * 32 + q * 8];

        // ---- layer 1: H1 = tanh(b1 + Wih1@H0 + Whh1@H1) ----
        f4 a1[4];
        #pragma unroll
        for (int mt = 0; mt < 4; ++mt) a1[mt] = MFMA(wi1[mt][0], nh0f[0], bias1[mt]);
        #pragma unroll
        for (int mt = 0; mt < 4; ++mt) a1[mt] = MFMA(wi1[mt][1], nh0f[1], a1[mt]);
        #pragma unroll
        for (int mt = 0; mt < 4; ++mt) a1[mt] = MFMA(wh1[mt][0], h1f[0], a1[mt]);
        #pragma unroll
        for (int mt = 0; mt < 4; ++mt) a1[mt] = MFMA(wh1[mt][1], h1f[1], a1[mt]);
        #pragma unroll
        for (int mt = 0; mt < 4; ++mt) {
            H4U u;
            u.p[0] = pkrtz(tanh_fast(a1[mt][0]), tanh_fast(a1[mt][1]));
            u.p[1] = pkrtz(tanh_fast(a1[mt][2]), tanh_fast(a1[mt][3]));
            *(h4*)&Hb[1][n * 72 + mt * 16 + q * 4] = u.v;
        }
        __builtin_amdgcn_wave_barrier();
        #pragma unroll
        for (int kt = 0; kt < 2; ++kt)
            h1f[kt] = *(const h8*)&Hb[1][n * 72 + kt * 32 + q * 8];

        h0f[0] = nh0f[0]; h0f[1] = nh0f[1];
        xc = xnx;
    }

    // ---- FC head: out[bseq+n] = sum_k fcw[k]*h1[k][n] + fcb ----
    float s = 0.f;
    #pragma unroll
    for (int kt = 0; kt < 2; ++kt)
        #pragma unroll
        for (int j = 0; j < 8; ++j)
            s += (float)h1f[kt][j] * fcw[32 * kt + 8 * q + j];
    s += __shfl_xor(s, 16, 64);
    s += __shfl_xor(s, 32, 64);
    if (q == 0) out[bseq + n] = s + fcb[0];
}

extern "C" void kernel_launch(void* const* d_in, const int* in_sizes, int n_in,
                              void* d_out, int out_size, void* d_ws, size_t ws_size,
                              hipStream_t stream) {
    const float* x    = (const float*)d_in[0];
    const float* Wih0 = (const float*)d_in[1];
    const float* Whh0 = (const float*)d_in[2];
    const float* bih0 = (const float*)d_in[3];
    const float* bhh0 = (const float*)d_in[4];
    const float* Wih1 = (const float*)d_in[5];
    const float* Whh1 = (const float*)d_in[6];
    const float* bih1 = (const float*)d_in[7];
    const float* bhh1 = (const float*)d_in[8];
    const float* fcw  = (const float*)d_in[9];
    const float* fcb  = (const float*)d_in[10];
    float* out = (float*)d_out;

    rnn2_mfma<<<dim3(NBLK), dim3(64), 0, stream>>>(
        x, Wih0, Whh0, bih0, bhh0, Wih1, Whh1, bih1, bhh1, fcw, fcb, out);
}

// Round 5
// 264.623 us; speedup vs baseline: 3.1617x; 1.8120x over previous
//
#include <hip/hip_runtime.h>

#define T_STEPS 512
#define BATCH   2048
#define HID     64
#define IN0     8
#define SPW     16              // sequences per group (MFMA N dim)
#define NBLK    (BATCH / SPW)   // 128 blocks, 4 waves each

typedef _Float16 h2 __attribute__((ext_vector_type(2)));
typedef _Float16 h4 __attribute__((ext_vector_type(4)));
typedef _Float16 h8 __attribute__((ext_vector_type(8)));
typedef float    f4 __attribute__((ext_vector_type(4)));

#define MFMA(a, b, c) __builtin_amdgcn_mfma_f32_16x16x32_f16((a), (b), (c), 0, 0, 0)

union F8 { h8 v; h2 p[4]; };
union H4U { h4 v; h2 p[2]; };

__device__ __forceinline__ h2 pkrtz(float a, float b) {
    return __builtin_bit_cast(h2, __builtin_amdgcn_cvt_pkrtz(a, b));
}

// tanh(x) = 1 - 2/(exp(2x)+1); saturates correctly at +/-inf.
__device__ __forceinline__ float tanh_fast(float x) {
    float e = __builtin_amdgcn_exp2f(x * 2.885390081777927f);
    return 1.0f - 2.0f * __builtin_amdgcn_rcpf(e + 1.0f);
}

__global__ __launch_bounds__(256, 1)
void rnn2_mfma(const float* __restrict__ x,
               const float* __restrict__ Wih0, const float* __restrict__ Whh0,
               const float* __restrict__ bih0, const float* __restrict__ bhh0,
               const float* __restrict__ Wih1, const float* __restrict__ Whh1,
               const float* __restrict__ bih1, const float* __restrict__ bhh1,
               const float* __restrict__ fcw,  const float* __restrict__ fcb,
               float* __restrict__ out) {
    const int tid  = threadIdx.x;
    const int w    = tid >> 6;    // wave id = m-tile (H rows 16w..16w+15)
    const int lane = tid & 63;
    const int n    = lane & 15;   // A row-in-tile / B,C column (sequence)
    const int q    = lane >> 4;   // quad: k-block for A/B, row-block for C
    const int bseq = blockIdx.x * SPW;

    // H buffers: [n][k] f16, k-stride 72 (+8 pad); double-buffered by t&1
    __shared__ __align__(16) _Float16 H0b[2][SPW * 72];
    __shared__ __align__(16) _Float16 H1b[2][SPW * 72];
    __shared__ float red[4][SPW];

    // ---- resident A-fragments for rows 16w+n: slot j <-> k = 32kt+8q+j ----
    h8 wh0[2], wi1[2], wh1[2];
    const int row = 16 * w + n;
    #pragma unroll
    for (int kt = 0; kt < 2; ++kt) {
        const int k0 = 32 * kt + 8 * q;
        {
            const float4* p = (const float4*)(Whh0 + row * HID + k0);
            float4 a = p[0], b = p[1];
            F8 f; f.p[0] = pkrtz(a.x, a.y); f.p[1] = pkrtz(a.z, a.w);
                  f.p[2] = pkrtz(b.x, b.y); f.p[3] = pkrtz(b.z, b.w);
            wh0[kt] = f.v;
        }
        {
            const float4* p = (const float4*)(Wih1 + row * HID + k0);
            float4 a = p[0], b = p[1];
            F8 f; f.p[0] = pkrtz(a.x, a.y); f.p[1] = pkrtz(a.z, a.w);
                  f.p[2] = pkrtz(b.x, b.y); f.p[3] = pkrtz(b.z, b.w);
            wi1[kt] = f.v;
        }
        {
            const float4* p = (const float4*)(Whh1 + row * HID + k0);
            float4 a = p[0], b = p[1];
            F8 f; f.p[0] = pkrtz(a.x, a.y); f.p[1] = pkrtz(a.z, a.w);
                  f.p[2] = pkrtz(b.x, b.y); f.p[3] = pkrtz(b.z, b.w);
            wh1[kt] = f.v;
        }
    }
    // Wih0 (64x8), K zero-padded; slot 0 holds k=2q,2q+1 (X B-frag matches)
    h8 wi0;
    {
        const float2 ww = *(const float2*)(Wih0 + row * IN0 + 2 * q);
        F8 f; f.p[0] = pkrtz(ww.x, ww.y);
        f.p[1] = pkrtz(0.f, 0.f); f.p[2] = f.p[1]; f.p[3] = f.p[1];
        wi0 = f.v;
    }
    // biases / fc weights in C-layout: reg r <-> row 16w + 4q + r
    f4 bias0, bias1, fcv;
    #pragma unroll
    for (int r = 0; r < 4; ++r) {
        const int i = 16 * w + 4 * q + r;
        bias0[r] = bih0[i] + bhh0[i];
        bias1[r] = bih1[i] + bhh1[i];
        fcv[r]   = fcw[i];
    }
    const float fcb0 = fcb[0];
    const f4 zero = {0.f, 0.f, 0.f, 0.f};

    // x: lane (q,n) streams x[bseq+n][t][2q..2q+1]
    const float* xp = x + ((size_t)(bseq + n) * T_STEPS) * IN0 + 2 * q;
    float2 xc = *(const float2*)xp;

    h8 h0f[2] = {}; h8 h1f[2] = {};   // H0_{t-1}, H1_{t-2} B-frags (start 0)

    // hoisted Wih0@x_0 + bias0
    f4 a0x;
    {
        F8 xf; xf.p[0] = pkrtz(xc.x, xc.y);
        xf.p[1] = pkrtz(0.f, 0.f); xf.p[2] = xf.p[1]; xf.p[3] = xf.p[1];
        a0x = MFMA(wi0, xf.v, bias0);
    }

    #pragma unroll 2
    for (int t = 0; t < T_STEPS; ++t) {
        const int tn = (t + 1 < T_STEPS) ? t + 1 : t;
        const float2 xnx = *(const float2*)(xp + tn * IN0);
        const int bf = t & 1;

        // ---- layer0(t): a0 = a0x + Whh0@H0_{t-1}  (2 indep chains) ----
        f4 acch = MFMA(wh0[0], h0f[0], zero);
        acch    = MFMA(wh0[1], h0f[1], acch);

        // ---- layer1(t-1): a1 = b1 + Wih1@H0_{t-1} + Whh1@H1_{t-2} ----
        f4 c1 = MFMA(wi1[0], h0f[0], bias1);
        c1    = MFMA(wi1[1], h0f[1], c1);
        f4 c2 = MFMA(wh1[0], h1f[0], zero);
        c2    = MFMA(wh1[1], h1f[1], c2);

        // H0_t = tanh(a0) -> LDS
        {
            const f4 a0 = a0x + acch;
            H4U u;
            u.p[0] = pkrtz(tanh_fast(a0[0]), tanh_fast(a0[1]));
            u.p[1] = pkrtz(tanh_fast(a0[2]), tanh_fast(a0[3]));
            *(h4*)&H0b[bf][n * 72 + w * 16 + q * 4] = u.v;
        }
        // H1_{t-1} = tanh(a1) -> LDS (t=0: true H1_{-1}=0)
        {
            const f4 a1 = c1 + c2;
            H4U u;
            u.p[0] = pkrtz(tanh_fast(a1[0]), tanh_fast(a1[1]));
            u.p[1] = pkrtz(tanh_fast(a1[2]), tanh_fast(a1[3]));
            if (t == 0) { u.p[0] = pkrtz(0.f, 0.f); u.p[1] = u.p[0]; }
            *(h4*)&H1b[bf][n * 72 + w * 16 + q * 4] = u.v;
        }

        // hoisted Wih0@x_{t+1} + bias0 (independent of the barrier)
        {
            F8 xf; xf.p[0] = pkrtz(xnx.x, xnx.y);
            xf.p[1] = pkrtz(0.f, 0.f); xf.p[2] = xf.p[1]; xf.p[3] = xf.p[1];
            a0x = MFMA(wi0, xf.v, bias0);
        }
        xc = xnx;

        __syncthreads();

        #pragma unroll
        for (int kt = 0; kt < 2; ++kt) {
            h0f[kt] = *(const h8*)&H0b[bf][n * 72 + kt * 32 + q * 8];
            h1f[kt] = *(const h8*)&H1b[bf][n * 72 + kt * 32 + q * 8];
        }
    }

    // ---- epilogue: layer1(T-1) from h0f=H0_{511}, h1f=H1_{510} ----
    f4 c1 = MFMA(wi1[0], h0f[0], bias1);
    c1    = MFMA(wi1[1], h0f[1], c1);
    f4 c2 = MFMA(wh1[0], h1f[0], zero);
    c2    = MFMA(wh1[1], h1f[1], c2);
    const f4 a1 = c1 + c2;

    // FC head: per-lane dot over its 4 rows, reduce q, then cross-wave
    float s = 0.f;
    #pragma unroll
    for (int r = 0; r < 4; ++r) s += fcv[r] * tanh_fast(a1[r]);
    s += __shfl_xor(s, 16, 64);
    s += __shfl_xor(s, 32, 64);
    if (lane < 16) red[w][n] = s;    // q==0 lanes
    __syncthreads();
    if (tid < SPW)
        out[bseq + tid] = red[0][tid] + red[1][tid] + red[2][tid] + red[3][tid] + fcb0;
}

extern "C" void kernel_launch(void* const* d_in, const int* in_sizes, int n_in,
                              void* d_out, int out_size, void* d_ws, size_t ws_size,
                              hipStream_t stream) {
    const float* x    = (const float*)d_in[0];
    const float* Wih0 = (const float*)d_in[1];
    const float* Whh0 = (const float*)d_in[2];
    const float* bih0 = (const float*)d_in[3];
    const float* bhh0 = (const float*)d_in[4];
    const float* Wih1 = (const float*)d_in[5];
    const float* Whh1 = (const float*)d_in[6];
    const float* bih1 = (const float*)d_in[7];
    const float* bhh1 = (const float*)d_in[8];
    const float* fcw  = (const float*)d_in[9];
    const float* fcb  = (const float*)d_in[10];
    float* out = (float*)d_out;

    rnn2_mfma<<<dim3(NBLK), dim3(256), 0, stream>>>(
        x, Wih0, Whh0, bih0, bhh0, Wih1, Whh1, bih1, bhh1, fcw, fcb, out);
}